// Round 15
// baseline (863.421 us; speedup 1.0000x reference)
//
#include <hip/hip_runtime.h>
#include <math.h>

using u16 = unsigned short;
using bf16x8 = __attribute__((ext_vector_type(8))) short;
using f32x4  = __attribute__((ext_vector_type(4))) float;

#define DEV static __device__ __forceinline__

DEV u16 f2bf(float f) {
  union { float f; unsigned u; } v; v.f = f;
  unsigned u = v.u + 0x7fffu + ((v.u >> 16) & 1u);
  return (u16)(u >> 16);
}

DEV void gload16(const void* g, void* l) {
  __builtin_amdgcn_global_load_lds(
      (const __attribute__((address_space(1))) void*)g,
      (__attribute__((address_space(3))) void*)l, 16, 0, 0);
}

// ---------------- prep kernels ----------------
__global__ void k_conv_bf16(const float* __restrict__ in, u16* __restrict__ out, int n) {
  int i = blockIdx.x * 256 + threadIdx.x;
  if (i < n) out[i] = f2bf(in[i]);
}

// in: f32 [K][Nin] row-major ; out: bf16 [Nout][K] (n-major).
// pack==1: n' = d2*48+j maps to n = d2*47+j for j<47, j==47 -> 0 (pad).
__global__ void k_transconv(const float* __restrict__ in, u16* __restrict__ out,
                            int K, int Nin, int Nout, int pack) {
  __shared__ float t[32][33];
  int kb = blockIdx.x * 32, nb = blockIdx.y * 32;
  int tx = threadIdx.x & 31, ty = threadIdx.x >> 5;  // 32 x 8
  #pragma unroll
  for (int i = 0; i < 4; ++i) {
    int k = kb + ty + i * 8;
    int no = nb + tx;
    float v = 0.f;
    if (k < K && no < Nout) {
      if (pack) {
        int r = no % 48;
        if (r < 47) v = in[(size_t)k * Nin + (no / 48) * 47 + r];
      } else {
        v = in[(size_t)k * Nin + no];
      }
    }
    t[ty + i * 8][tx] = v;
  }
  __syncthreads();
  #pragma unroll
  for (int i = 0; i < 4; ++i) {
    int no = nb + ty + i * 8;
    int k = kb + tx;
    if (no < Nout && k < K) out[(size_t)no * K + k] = f2bf(t[tx][ty + i * 8]);
  }
}

// ---------------- GEMM + ReLU (BM=128,BN=128,BK=32, 4 waves) for GEMM1/2 ----------------
__global__ __launch_bounds__(256)
void k_gemm_relu(const u16* __restrict__ A, const u16* __restrict__ Bt,
                 const float* __restrict__ bias, u16* __restrict__ C,
                 int N, int K) {
  constexpr int BM = 128, BN = 128, BK = 32;
  __shared__ __align__(16) u16 lds[(BM + BN) * BK];
  int tid = threadIdx.x, w = tid >> 6, lane = tid & 63;
  int bn = blockIdx.x, bm = blockIdx.y;
  int brow = bm * BM, bcol = bn * BN;
  int wm = w >> 1, wn = w & 1;
  int fr = lane & 15, fg = lane >> 4;
  f32x4 acc[4][4];
  #pragma unroll
  for (int i = 0; i < 4; ++i)
    #pragma unroll
    for (int j = 0; j < 4; ++j) acc[i][j] = (f32x4){0.f, 0.f, 0.f, 0.f};

  constexpr int ACH = BM * BK / 8;
  constexpr int CALLS = (BM + BN) * BK / 8 / 64;

  for (int kt = 0; kt < K; kt += BK) {
    for (int j = 0; j * 4 + w < CALLS; ++j) {
      int cb = (j * 4 + w) * 64;
      int c = cb + lane;
      const u16* g;
      if (c < ACH) {
        int row = c >> 2, c8 = c & 3;
        g = A + (size_t)(brow + row) * K + kt + c8 * 8;
      } else {
        int b = c - ACH;
        int nn = b >> 2, c8 = b & 3;
        g = Bt + (size_t)(bcol + nn) * K + kt + c8 * 8;
      }
      gload16(g, &lds[cb * 8]);
    }
    asm volatile("s_waitcnt vmcnt(0)" ::: "memory");
    __syncthreads();

    const u16* Al = lds;
    const u16* Bl = lds + BM * BK;
    bf16x8 af[4], bfr[4];
    #pragma unroll
    for (int mi = 0; mi < 4; ++mi)
      af[mi] = *(const bf16x8*)&Al[(wm * 64 + mi * 16 + fr) * BK + fg * 8];
    #pragma unroll
    for (int ni = 0; ni < 4; ++ni)
      bfr[ni] = *(const bf16x8*)&Bl[(wn * 64 + ni * 16 + fr) * BK + fg * 8];
    #pragma unroll
    for (int mi = 0; mi < 4; ++mi)
      #pragma unroll
      for (int ni = 0; ni < 4; ++ni)
        acc[mi][ni] = __builtin_amdgcn_mfma_f32_16x16x32_bf16(af[mi], bfr[ni], acc[mi][ni], 0, 0, 0);
    __syncthreads();
  }

  #pragma unroll
  for (int ni = 0; ni < 4; ++ni) {
    int col = bcol + wn * 64 + ni * 16 + fr;
    float bb = bias[col];
    #pragma unroll
    for (int mi = 0; mi < 4; ++mi) {
      #pragma unroll
      for (int q = 0; q < 4; ++q) {
        int row = brow + wm * 64 + mi * 16 + fg * 4 + q;
        float vv = acc[mi][ni][q] + bb;
        C[(size_t)row * N + col] = f2bf(vv > 0.f ? vv : 0.f);
      }
    }
  }
}

// ------- GEMM3 fused with spline: BM=256, BN=192, BK=32, 4 waves, 2 blocks/CU -------
// Traffic-minimal proven-parts config: staged bytes 3.75 GB (0.70x the BM=128 kernels),
// per-wave 64x192 output (acc[4][12]; R9-proven register budget at 2 blk/CU).
// LDS dbuf 2x28672 B (A 16K + B 12K per buffer) -> request 57344 -> 2 blocks/CU.
// Uniform 7 gload16/thread/tile (A:4 units, B:3 units of 64 rows). R13-verified
// 64B-row swizzle: stage csrc = (tid&3)^((tid>>3)&3); read chunk = fg^((fr>>1)&3).
// R7-proven drain loop: ISSUE_ALL(t+1); COMPUTE (16 ds_read_b128 -> 48 MFMA/wave);
// vmcnt(0); barrier. 32 tiles (K=1024/BK=32).
__global__ __launch_bounds__(256, 2)
void k_gemm3_fused(const u16* __restrict__ A, const u16* __restrict__ Bt,
                   const float* __restrict__ b2, const float* __restrict__ x2,
                   float* __restrict__ y2, float* __restrict__ ldpart) {
  extern __shared__ char smem[];
  const int tid = threadIdx.x, w = tid >> 6, lane = tid & 63;
  const int fr = lane & 15, fg = lane >> 4;

  const int bid = blockIdx.x;                     // 4096 blocks = 64 bm x 64 bn
  const int bm = bid >> 6;
  const int bn = ((bid & 7) << 3) | ((bid >> 3) & 7);  // XCD-chunked L2 map
  const int brow = bm * 256;

  // staging: row = tid>>2 (+64 per unit), chunk c = tid&3 of the 64B row.
  // source chunk pre-XOR'd: csrc = c ^ ((row>>1)&3); LDS dest linear (rule #21).
  const int csrc = (tid & 3) ^ ((tid >> 3) & 3);
  const u16* gA0 = A + (size_t)(brow + (tid >> 2)) * 1024 + csrc * 8;
  const u16* gB0 = Bt + (size_t)(bn * 192 + (tid >> 2)) * 1024 + csrc * 8;

#define ISSUE_ALL(t1) {                                               \
    const size_t ko_ = (size_t)(t1) * 32;                             \
    char* p_ = smem + ((t1) & 1) * 28672 + tid * 16;                  \
    gload16(gA0 + ko_, p_);                                           \
    gload16(gA0 + 65536 + ko_, p_ + 4096);                            \
    gload16(gA0 + 131072 + ko_, p_ + 8192);                           \
    gload16(gA0 + 196608 + ko_, p_ + 12288);                          \
    gload16(gB0 + ko_, p_ + 16384);                                   \
    gload16(gB0 + 65536 + ko_, p_ + 20480);                           \
    gload16(gB0 + 131072 + ko_, p_ + 24576); }

  // swizzled read chunk offset (bytes): chunk = fg ^ ((row>>1)&3), (row>>1)&3 == (fr>>1)&3
  const int sc = ((fg ^ ((fr >> 1) & 3)) << 4);

  f32x4 acc[4][12];
  #pragma unroll
  for (int m = 0; m < 4; ++m)
    #pragma unroll
    for (int n = 0; n < 12; ++n) acc[m][n] = (f32x4){0.f, 0.f, 0.f, 0.f};

  ISSUE_ALL(0);
  asm volatile("s_waitcnt vmcnt(0)" ::: "memory");
  __syncthreads();

  for (int t = 0; t < 32; ++t) {
    if (t < 31) ISSUE_ALL(t + 1);
    const char* Ab = smem + (t & 1) * 28672;
    const char* Bb = Ab + 16384;
    bf16x8 a[4];
    #pragma unroll
    for (int m = 0; m < 4; ++m)
      a[m] = *(const bf16x8*)(Ab + (w * 64 + m * 16 + fr) * 64 + sc);
    __builtin_amdgcn_s_setprio(1);
    #pragma unroll
    for (int n = 0; n < 12; ++n) {
      bf16x8 b = *(const bf16x8*)(Bb + (n * 16 + fr) * 64 + sc);
      #pragma unroll
      for (int m = 0; m < 4; ++m)
        acc[m][n] = __builtin_amdgcn_mfma_f32_16x16x32_bf16(a[m], b, acc[m][n], 0, 0, 0);
    }
    __builtin_amdgcn_s_setprio(0);
    asm volatile("s_waitcnt vmcnt(0)" ::: "memory");
    __syncthreads();
  }

  // ---- epilogue: 4 rounds; round r: wave r writes its 64x192 sub-tile to 4 slots
  // [64][49] f32 (50176 B), 256 threads eval (64 rows x 4 d2-groups), ld reduce ----
  float* fl = (float*)smem;
  float* ldacc = (float*)(smem + 50176);  // [64][4] f32
  #pragma unroll
  for (int r = 0; r < 4; ++r) {
    if (w == r) {
      #pragma unroll
      for (int m = 0; m < 4; ++m)
        #pragma unroll
        for (int n = 0; n < 12; ++n) {
          const int g = n / 3, j = n % 3;
          #pragma unroll
          for (int q = 0; q < 4; ++q)
            fl[g * 3136 + (m * 16 + fg * 4 + q) * 49 + j * 16 + fr] = acc[m][n][q];
        }
    }
    __syncthreads();
    {
      const int g = tid >> 6, rr = tid & 63;
      const float* pr = fl + g * 3136 + rr * 49;
      const int grow = brow + r * 64 + rr;
      const int d2 = bn * 4 + g;
      const float* bb = b2 + (size_t)d2 * 47;

      float wv[16], hv[16];
      #pragma unroll
      for (int j = 0; j < 16; ++j) wv[j] = pr[j] + bb[j];
      #pragma unroll
      for (int j = 0; j < 16; ++j) hv[j] = pr[16 + j] + bb[16 + j];

      float x = x2[(size_t)grow * 256 + d2];
      float xc = fminf(fmaxf(x, -3.f), 3.f);

      float mw = wv[0];
      #pragma unroll
      for (int j = 1; j < 16; ++j) mw = fmaxf(mw, wv[j]);
      float sw = 0.f;
      #pragma unroll
      for (int j = 0; j < 16; ++j) { wv[j] = __expf(wv[j] - mw); sw += wv[j]; }
      float scw = 0.984f / sw;

      float mh = hv[0];
      #pragma unroll
      for (int j = 1; j < 16; ++j) mh = fmaxf(mh, hv[j]);
      float sh = 0.f;
      #pragma unroll
      for (int j = 0; j < 16; ++j) { hv[j] = __expf(hv[j] - mh); sh += hv[j]; }
      float sch = 0.984f / sh;

      int idx = 0;
      float xk = -3.f, cum = 0.f;
      #pragma unroll
      for (int i = 1; i <= 15; ++i) {
        cum += 0.001f + wv[i - 1] * scw;
        float cwi = 6.f * cum - 3.f;
        if (xc >= cwi) { idx = i; xk = cwi; }
      }
      float yk = -3.f, cumh = 0.f;
      #pragma unroll
      for (int i = 1; i <= 15; ++i) {
        cumh += 0.001f + hv[i - 1] * sch;
        float chi = 6.f * cumh - 3.f;
        if (i == idx) yk = chi;
      }
      float wk = 1.f, hk = 1.f;
      #pragma unroll
      for (int i = 0; i < 16; ++i) {
        if (i == idx) {
          wk = 6.f * (0.001f + wv[i] * scw);
          hk = 6.f * (0.001f + hv[i] * sch);
        }
      }
      float dk = 1.f, dk1 = 1.f;
      #pragma unroll
      for (int i = 1; i <= 15; ++i) {
        float u = pr[32 + i - 1] + bb[32 + i - 1];
        float e = __expf(u);
        float dd = 0.001f + (u > 15.f ? u : log1pf(e));
        if (i == idx) dk = dd;
        if (i == idx + 1) dk1 = dd;
      }

      float sk = hk / wk;
      float th = (xc - xk) / wk;
      float om = 1.f - th;
      float t1m = th * om;
      float den = sk + (dk + dk1 - 2.f * sk) * t1m;
      float y = yk + hk * (sk * th * th + dk * t1m) / den;
      float deriv = sk * sk * (dk1 * th * th + 2.f * sk * t1m + dk * om * om) / (den * den);
      bool inside = (x > -3.f) && (x < 3.f);
      float yout = inside ? y : x;
      float ld = inside ? __logf(deriv) : 0.f;

      y2[(size_t)grow * 256 + d2] = yout;
      ldacc[rr * 4 + g] = ld;
    }
    __syncthreads();
    if (tid < 64) {
      float s = ldacc[tid * 4] + ldacc[tid * 4 + 1] + ldacc[tid * 4 + 2] + ldacc[tid * 4 + 3];
      ldpart[(size_t)bn * 16384 + brow + r * 64 + tid] = s;
    }
    __syncthreads();
  }
}

__global__ void k_reduce_ld(const float* __restrict__ part, float* __restrict__ out) {
  int r = blockIdx.x * 256 + threadIdx.x;
  float s = 0.f;
  for (int j = 0; j < 64; ++j) s += part[(size_t)j * 16384 + r];
  out[r] = s;
}

// ---------------- launch ----------------
extern "C" void kernel_launch(void* const* d_in, const int* in_sizes, int n_in,
                              void* d_out, int out_size, void* d_ws, size_t ws_size,
                              hipStream_t stream) {
  const float* x1 = (const float*)d_in[0];
  const float* x2 = (const float*)d_in[1];
  const float* W0 = (const float*)d_in[2];
  const float* b0 = (const float*)d_in[3];
  const float* W1 = (const float*)d_in[4];
  const float* b1 = (const float*)d_in[5];
  const float* W2 = (const float*)d_in[6];
  const float* b2 = (const float*)d_in[7];
  float* y2 = (float*)d_out;
  float* logdet = y2 + (size_t)16384 * 256;

  char* ws = (char*)d_ws;
  u16* W2t = (u16*)ws;                                   // 25165824
  u16* W0t = (u16*)(ws + 25165824);                      //   524288
  u16* W1t = (u16*)(ws + 25165824 + 524288);             //  2097152
  u16* x1b = (u16*)(ws + 27787264);                      //  8388608
  float* ldp = (float*)(ws + 27787264);                  // aliases x1b (dead by GEMM3); 64*16384*4=4MB
  u16* h1  = (u16*)(ws + 36175872);                      // 33554432
  u16* h2  = (u16*)(ws + 69730304);                      // 33554432

  hipFuncSetAttribute((const void*)k_gemm3_fused,
                      hipFuncAttributeMaxDynamicSharedMemorySize, 57344);

  k_conv_bf16<<<16384, 256, 0, stream>>>(x1, x1b, 16384 * 256);
  k_transconv<<<dim3(8, 32), 256, 0, stream>>>(W0, W0t, 256, 1024, 1024, 0);
  k_transconv<<<dim3(32, 32), 256, 0, stream>>>(W1, W1t, 1024, 1024, 1024, 0);
  k_transconv<<<dim3(32, 384), 256, 0, stream>>>(W2, W2t, 1024, 12032, 12288, 1);

  k_gemm_relu<<<dim3(8, 128), 256, 0, stream>>>(x1b, W0t, b0, h1, 1024, 256);
  k_gemm_relu<<<dim3(8, 128), 256, 0, stream>>>(h1, W1t, b1, h2, 1024, 1024);
  k_gemm3_fused<<<4096, 256, 57344, stream>>>(h2, W2t, b2, x2, y2, ldp);
  k_reduce_ld<<<64, 256, 0, stream>>>(ldp, logdet);
}

// Round 16
// 725.628 us; speedup vs baseline: 1.1899x; 1.1899x over previous
//
#include <hip/hip_runtime.h>
#include <math.h>

using u16 = unsigned short;
using bf16x8 = __attribute__((ext_vector_type(8))) short;
using f32x4  = __attribute__((ext_vector_type(4))) float;

#define DEV static __device__ __forceinline__

DEV u16 f2bf(float f) {
  union { float f; unsigned u; } v; v.f = f;
  unsigned u = v.u + 0x7fffu + ((v.u >> 16) & 1u);
  return (u16)(u >> 16);
}

DEV void gload16(const void* g, void* l) {
  __builtin_amdgcn_global_load_lds(
      (const __attribute__((address_space(1))) void*)g,
      (__attribute__((address_space(3))) void*)l, 16, 0, 0);
}

// ---------------- prep kernels ----------------
__global__ void k_conv_bf16(const float* __restrict__ in, u16* __restrict__ out, int n) {
  int i = blockIdx.x * 256 + threadIdx.x;
  if (i < n) out[i] = f2bf(in[i]);
}

// in: f32 [K][Nin] row-major ; out (pack=0): bf16 [Nout][K] n-major.
// pack=1 (W2): n' = bn*192+r maps cols d2*47+j (pad j=47->0); output TILE-PACKED
// [bn][t][192][32] with the gemm3 LDS XOR swizzle baked in at 16B-chunk level.
__global__ void k_transconv(const float* __restrict__ in, u16* __restrict__ out,
                            int K, int Nin, int Nout, int pack) {
  __shared__ float t[32][33];
  int kb = blockIdx.x * 32, nb = blockIdx.y * 32;
  int tx = threadIdx.x & 31, ty = threadIdx.x >> 5;  // 32 x 8
  #pragma unroll
  for (int i = 0; i < 4; ++i) {
    int k = kb + ty + i * 8;
    int no = nb + tx;
    float v = 0.f;
    if (k < K && no < Nout) {
      if (pack) {
        int r = no % 48;
        if (r < 47) v = in[(size_t)k * Nin + (no / 48) * 47 + r];
      } else {
        v = in[(size_t)k * Nin + no];
      }
    }
    t[ty + i * 8][tx] = v;
  }
  __syncthreads();
  #pragma unroll
  for (int i = 0; i < 4; ++i) {
    int no = nb + ty + i * 8;
    int k = kb + tx;
    if (no < Nout && k < K) {
      float v = t[tx][ty + i * 8];
      if (pack) {
        int r_ = no % 192, bn_ = no / 192;
        int t_ = k >> 5, c_ = k & 31;
        out[(((size_t)bn_ * 32 + t_) * 192 + r_) * 32
            + (((c_ >> 3) ^ ((r_ >> 1) & 3)) << 3) + (c_ & 7)] = f2bf(v);
      } else {
        out[(size_t)no * K + k] = f2bf(v);
      }
    }
  }
}

// ---------------- GEMM + ReLU (BM=128,BN=128,BK=32, 4 waves) for GEMM1/2 ----------------
// pack=1: write C TILE-PACKED [bm][t][128][32] (swizzle baked) for gemm3's A staging.
__global__ __launch_bounds__(256)
void k_gemm_relu(const u16* __restrict__ A, const u16* __restrict__ Bt,
                 const float* __restrict__ bias, u16* __restrict__ C,
                 int N, int K, int pack) {
  constexpr int BM = 128, BN = 128, BK = 32;
  __shared__ __align__(16) u16 lds[(BM + BN) * BK];
  int tid = threadIdx.x, w = tid >> 6, lane = tid & 63;
  int bn = blockIdx.x, bm = blockIdx.y;
  int brow = bm * BM, bcol = bn * BN;
  int wm = w >> 1, wn = w & 1;
  int fr = lane & 15, fg = lane >> 4;
  f32x4 acc[4][4];
  #pragma unroll
  for (int i = 0; i < 4; ++i)
    #pragma unroll
    for (int j = 0; j < 4; ++j) acc[i][j] = (f32x4){0.f, 0.f, 0.f, 0.f};

  constexpr int ACH = BM * BK / 8;
  constexpr int CALLS = (BM + BN) * BK / 8 / 64;

  for (int kt = 0; kt < K; kt += BK) {
    for (int j = 0; j * 4 + w < CALLS; ++j) {
      int cb = (j * 4 + w) * 64;
      int c = cb + lane;
      const u16* g;
      if (c < ACH) {
        int row = c >> 2, c8 = c & 3;
        g = A + (size_t)(brow + row) * K + kt + c8 * 8;
      } else {
        int b = c - ACH;
        int nn = b >> 2, c8 = b & 3;
        g = Bt + (size_t)(bcol + nn) * K + kt + c8 * 8;
      }
      gload16(g, &lds[cb * 8]);
    }
    asm volatile("s_waitcnt vmcnt(0)" ::: "memory");
    __syncthreads();

    const u16* Al = lds;
    const u16* Bl = lds + BM * BK;
    bf16x8 af[4], bfr[4];
    #pragma unroll
    for (int mi = 0; mi < 4; ++mi)
      af[mi] = *(const bf16x8*)&Al[(wm * 64 + mi * 16 + fr) * BK + fg * 8];
    #pragma unroll
    for (int ni = 0; ni < 4; ++ni)
      bfr[ni] = *(const bf16x8*)&Bl[(wn * 64 + ni * 16 + fr) * BK + fg * 8];
    #pragma unroll
    for (int mi = 0; mi < 4; ++mi)
      #pragma unroll
      for (int ni = 0; ni < 4; ++ni)
        acc[mi][ni] = __builtin_amdgcn_mfma_f32_16x16x32_bf16(af[mi], bfr[ni], acc[mi][ni], 0, 0, 0);
    __syncthreads();
  }

  #pragma unroll
  for (int ni = 0; ni < 4; ++ni) {
    int col = bcol + wn * 64 + ni * 16 + fr;
    float bb = bias[col];
    #pragma unroll
    for (int mi = 0; mi < 4; ++mi) {
      #pragma unroll
      for (int q = 0; q < 4; ++q) {
        int row = brow + wm * 64 + mi * 16 + fg * 4 + q;
        float vv = acc[mi][ni][q] + bb;
        u16 ov = f2bf(vv > 0.f ? vv : 0.f);
        if (pack) {
          int t_ = col >> 5, c_ = col & 31, r_ = row & 127;
          C[(((size_t)(row >> 7) * 32 + t_) * 128 + r_) * 32
            + (((c_ >> 3) ^ ((r_ >> 1) & 3)) << 3) + (c_ & 7)] = ov;
        } else {
          C[(size_t)row * N + col] = ov;
        }
      }
    }
  }
}

// ------- GEMM3 fused with spline: BM=128, BN=192, BK=32, 4 waves, depth-2 ring -------
// R14's verified kernel with ONE change: staging sources are TILE-PACKED arrays
// (Apack [bm][t][128][32], Bpack [bn][t][192][32], swizzle pre-baked) so every
// gload16 wave-request is a CONTIGUOUS 1KB stream (m97's address pattern) instead
// of 16 rows strided 2KB -- even L2-channel spread on the fill path.
// Ring: 3 slots x 20480 B (61440 -> 2 blocks/CU); stage t+2 at top of t; vmcnt(5)
// + raw s_barrier at end of t. LDS image identical to R14 (same ds_read formulas).
__global__ __launch_bounds__(256, 2)
void k_gemm3_fused(const u16* __restrict__ Apack, const u16* __restrict__ Bpack,
                   const float* __restrict__ b2, const float* __restrict__ x2,
                   float* __restrict__ y2, float* __restrict__ ldpart) {
  extern __shared__ char smem[];
  const int tid = threadIdx.x, w = tid >> 6, lane = tid & 63;
  const int wm = w >> 1, wn = w & 1;
  const int fr = lane & 15, fg = lane >> 4;

  const int bid = blockIdx.x;                     // 8192 blocks
  const int bm = bid >> 6;                        // 0..127
  const int bn = ((bid & 7) << 3) | ((bid >> 3) & 7);  // 0..63, XCD-chunked
  const int brow = bm * 128;

  // packed bases: A tile = 4096 u16 (8KB); B tile = 6144 u16 (12KB)
  const u16* gA0 = Apack + (size_t)bm * 131072 + tid * 8;   // 32 tiles x 4096
  const u16* gB0 = Bpack + (size_t)bn * 196608 + tid * 8;   // 32 tiles x 6144

#define STAGE(t1, sb) {                                               \
    const u16* pa_ = gA0 + (size_t)(t1) * 4096;                       \
    const u16* pb_ = gB0 + (size_t)(t1) * 6144;                       \
    char* p_ = smem + (sb) + tid * 16;                                \
    gload16(pa_, p_);                                                 \
    gload16(pa_ + 2048, p_ + 4096);                                   \
    gload16(pb_, p_ + 8192);                                          \
    gload16(pb_ + 2048, p_ + 12288);                                  \
    gload16(pb_ + 4096, p_ + 16384); }

  // swizzled read chunk offset (bytes): chunk = fg ^ ((row>>1)&3), (row>>1)&3 == (fr>>1)&3
  const int sc = ((fg ^ ((fr >> 1) & 3)) << 4);

  f32x4 acc[4][6];
  #pragma unroll
  for (int m = 0; m < 4; ++m)
    #pragma unroll
    for (int n = 0; n < 6; ++n) acc[m][n] = (f32x4){0.f, 0.f, 0.f, 0.f};

#define COMPUTE(sb) {                                                 \
    const char* Ab_ = smem + (sb);                                    \
    const char* Bb_ = Ab_ + 8192;                                     \
    bf16x8 b_[6];                                                     \
    _Pragma("unroll")                                                 \
    for (int n_ = 0; n_ < 6; ++n_)                                    \
      b_[n_] = *(const bf16x8*)(Bb_ + (wn * 96 + n_ * 16 + fr) * 64 + sc); \
    __builtin_amdgcn_s_setprio(1);                                    \
    _Pragma("unroll")                                                 \
    for (int m_ = 0; m_ < 4; ++m_) {                                  \
      bf16x8 a_ = *(const bf16x8*)(Ab_ + (wm * 64 + m_ * 16 + fr) * 64 + sc); \
      _Pragma("unroll")                                               \
      for (int n_ = 0; n_ < 6; ++n_)                                  \
        acc[m_][n_] = __builtin_amdgcn_mfma_f32_16x16x32_bf16(a_, b_[n_], acc[m_][n_], 0, 0, 0); \
    }                                                                 \
    __builtin_amdgcn_s_setprio(0); }

#define VMW(n) { asm volatile("s_waitcnt vmcnt(" #n ")" ::: "memory"); \
                 __builtin_amdgcn_sched_barrier(0); }
#define RBAR() { __builtin_amdgcn_s_barrier(); __builtin_amdgcn_sched_barrier(0); }

  // prologue: stage tiles 0,1; wait tile 0 (tile 1's 5 stay in flight)
  STAGE(0, 0); STAGE(1, 20480);
  VMW(5);
  RBAR();

  // t = 0..29 (unrolled by 3 for static slot bases); stage t+2 at top of t
  for (int j = 0; j < 10; ++j) {
    STAGE(3 * j + 2, 40960); COMPUTE(0);     VMW(5); RBAR();
    STAGE(3 * j + 3, 0);     COMPUTE(20480); VMW(5); RBAR();
    STAGE(3 * j + 4, 20480); COMPUTE(40960); VMW(5); RBAR();
  }
  // tail: t=30 (slot 0; tile 31's 5 outstanding), t=31 (slot 1)
  COMPUTE(0); VMW(0); RBAR();
  COMPUTE(20480);
  __syncthreads();

  // ---- epilogue (R7/R13/R14-proven): 2 row-half rounds; 4 slots [64][49] f32 ----
  float* ldacc = (float*)(smem + 50176);  // [128][4]
  float* fl = (float*)smem;
  #pragma unroll
  for (int rh = 0; rh < 2; ++rh) {
    if (wm == rh) {
      #pragma unroll
      for (int m = 0; m < 4; ++m)
        #pragma unroll
        for (int n = 0; n < 6; ++n) {
          const int g = wn * 2 + (n >= 3 ? 1 : 0);
          const int ci = (n % 3) * 16 + fr;
          #pragma unroll
          for (int q = 0; q < 4; ++q)
            fl[g * 3136 + (m * 16 + fg * 4 + q) * 49 + ci] = acc[m][n][q];
        }
    }
    __syncthreads();
    {
      const int g = tid >> 6, r = tid & 63;
      const float* pr = fl + g * 3136 + r * 49;
      const int grow = brow + rh * 64 + r;
      const int d2 = bn * 4 + g;
      const float* bb = b2 + (size_t)d2 * 47;

      float wv[16], hv[16];
      #pragma unroll
      for (int j = 0; j < 16; ++j) wv[j] = pr[j] + bb[j];
      #pragma unroll
      for (int j = 0; j < 16; ++j) hv[j] = pr[16 + j] + bb[16 + j];

      float x = x2[(size_t)grow * 256 + d2];
      float xc = fminf(fmaxf(x, -3.f), 3.f);

      float mw = wv[0];
      #pragma unroll
      for (int j = 1; j < 16; ++j) mw = fmaxf(mw, wv[j]);
      float sw = 0.f;
      #pragma unroll
      for (int j = 0; j < 16; ++j) { wv[j] = __expf(wv[j] - mw); sw += wv[j]; }
      float scw = 0.984f / sw;

      float mh = hv[0];
      #pragma unroll
      for (int j = 1; j < 16; ++j) mh = fmaxf(mh, hv[j]);
      float sh = 0.f;
      #pragma unroll
      for (int j = 0; j < 16; ++j) { hv[j] = __expf(hv[j] - mh); sh += hv[j]; }
      float sch = 0.984f / sh;

      int idx = 0;
      float xk = -3.f, cum = 0.f;
      #pragma unroll
      for (int i = 1; i <= 15; ++i) {
        cum += 0.001f + wv[i - 1] * scw;
        float cwi = 6.f * cum - 3.f;
        if (xc >= cwi) { idx = i; xk = cwi; }
      }
      float yk = -3.f, cumh = 0.f;
      #pragma unroll
      for (int i = 1; i <= 15; ++i) {
        cumh += 0.001f + hv[i - 1] * sch;
        float chi = 6.f * cumh - 3.f;
        if (i == idx) yk = chi;
      }
      float wk = 1.f, hk = 1.f;
      #pragma unroll
      for (int i = 0; i < 16; ++i) {
        if (i == idx) {
          wk = 6.f * (0.001f + wv[i] * scw);
          hk = 6.f * (0.001f + hv[i] * sch);
        }
      }
      float dk = 1.f, dk1 = 1.f;
      #pragma unroll
      for (int i = 1; i <= 15; ++i) {
        float u = pr[32 + i - 1] + bb[32 + i - 1];
        float e = __expf(u);
        float dd = 0.001f + (u > 15.f ? u : log1pf(e));
        if (i == idx) dk = dd;
        if (i == idx + 1) dk1 = dd;
      }

      float sk = hk / wk;
      float th = (xc - xk) / wk;
      float om = 1.f - th;
      float t1m = th * om;
      float den = sk + (dk + dk1 - 2.f * sk) * t1m;
      float y = yk + hk * (sk * th * th + dk * t1m) / den;
      float deriv = sk * sk * (dk1 * th * th + 2.f * sk * t1m + dk * om * om) / (den * den);
      bool inside = (x > -3.f) && (x < 3.f);
      float yout = inside ? y : x;
      float ld = inside ? __logf(deriv) : 0.f;

      y2[(size_t)grow * 256 + d2] = yout;
      ldacc[(rh * 64 + r) * 4 + g] = ld;
    }
    __syncthreads();
  }

  if (tid < 128) {
    float s = ldacc[tid * 4] + ldacc[tid * 4 + 1] + ldacc[tid * 4 + 2] + ldacc[tid * 4 + 3];
    ldpart[(size_t)bn * 16384 + brow + tid] = s;
  }
}

__global__ void k_reduce_ld(const float* __restrict__ part, float* __restrict__ out) {
  int r = blockIdx.x * 256 + threadIdx.x;
  float s = 0.f;
  for (int j = 0; j < 64; ++j) s += part[(size_t)j * 16384 + r];
  out[r] = s;
}

// ---------------- launch ----------------
extern "C" void kernel_launch(void* const* d_in, const int* in_sizes, int n_in,
                              void* d_out, int out_size, void* d_ws, size_t ws_size,
                              hipStream_t stream) {
  const float* x1 = (const float*)d_in[0];
  const float* x2 = (const float*)d_in[1];
  const float* W0 = (const float*)d_in[2];
  const float* b0 = (const float*)d_in[3];
  const float* W1 = (const float*)d_in[4];
  const float* b1 = (const float*)d_in[5];
  const float* W2 = (const float*)d_in[6];
  const float* b2 = (const float*)d_in[7];
  float* y2 = (float*)d_out;
  float* logdet = y2 + (size_t)16384 * 256;

  char* ws = (char*)d_ws;
  u16* W2p = (u16*)ws;                                   // packed 12288*1024*2 = 25165824
  u16* W0t = (u16*)(ws + 25165824);                      //   524288
  u16* W1t = (u16*)(ws + 25165824 + 524288);             //  2097152
  u16* x1b = (u16*)(ws + 27787264);                      //  8388608
  float* ldp = (float*)(ws + 27787264);                  // aliases x1b (dead by GEMM3); 64*16384*4=4MB
  u16* h1  = (u16*)(ws + 36175872);                      // 33554432
  u16* h2p = (u16*)(ws + 69730304);                      // packed 16384*1024*2 = 33554432

  hipFuncSetAttribute((const void*)k_gemm3_fused,
                      hipFuncAttributeMaxDynamicSharedMemorySize, 61440);

  k_conv_bf16<<<16384, 256, 0, stream>>>(x1, x1b, 16384 * 256);
  k_transconv<<<dim3(8, 32), 256, 0, stream>>>(W0, W0t, 256, 1024, 1024, 0);
  k_transconv<<<dim3(32, 32), 256, 0, stream>>>(W1, W1t, 1024, 1024, 1024, 0);
  k_transconv<<<dim3(32, 384), 256, 0, stream>>>(W2, W2p, 1024, 12032, 12288, 1);

  k_gemm_relu<<<dim3(8, 128), 256, 0, stream>>>(x1b, W0t, b0, h1, 1024, 256, 0);
  k_gemm_relu<<<dim3(8, 128), 256, 0, stream>>>(h1, W1t, b1, h2p, 1024, 1024, 1);
  k_gemm3_fused<<<8192, 256, 61440, stream>>>(h2p, W2p, b2, x2, y2, ldp);
  k_reduce_ld<<<64, 256, 0, stream>>>(ldp, logdet);
}